// Round 15
// baseline (101.098 us; speedup 1.0000x reference)
//
#include <hip/hip_runtime.h>

// CatNet_76553497084407 — SLAYER-style spiking CNN, fully collapsed over time.
//
// R22 = R21 (best: 97.1us bench, absmax 0.0) + unroll-2 on the conv quad
// loops (phase-2 qd, phase-4 q). Targets the "hidden VALU": measured VALU
// issue is ~1.7x the static FMA+epilogue count -> loop control, per-iter
// base-address recompute, sched boundaries at the #pragma unroll 1 edges.
// Unroll 2 halves that overhead and lets ds_read offsets fold across
// iteration pairs. FP accumulation order unchanged -> absmax 0.0.
// Live set ~110 VGPR (2x40 window + acc) under the 128 budget; R4-R6 spill
// cliff is the risk -> WRITE_SIZE tripwire (must stay ~tens of KB).
//
// Packed fp32 is EXCLUDED by arithmetic: 157.3 TF = 256x4x32x2x2.4GHz is
// the UNPACKED v_fma rate; pk_fma cannot beat scalar slot-for-slot on CDNA4.
// MFMA is EXCLUDED by exactness: taps k/50 and boundary resolution 2e-4
// don't survive bf16/fp16 operand rounding; no fp32-input MFMA exists.
//
// Final model (15 rounds): wave-ISSUE-SLOT + latency bound at ~2.2x the
// pure-VALU-issue floor.
//   time ~ slots: R9 +DS -> +16%; R12 +VMEM -> +170%; R13 -75% DS -> -15%;
//   R17 +25% work (at 2x occupancy!) -> +23%; R20/R21 small cuts -> small wins.
//   null: R8 (-conflicts, -divide), R11 (+barrier domains), R15 (prefetch).
//   negative: R14 (slot cut idling waves), R16 (weights SMEM->VMEM).
// If this round is null or spills, R21/R22-best is terminal.
//
// Kernel structure: ci-quad float4 interstage layouts (one ds_read_b128 =
// one window tap x 4 input channels), wave-uniform s_load weights, 16-wave
// mapping, wave=channel phase 1, exact c/50 LDS rate table, 2e-4 risky
// threshold with 50-step sim fallback, no-ballot pooled rate, float4 dense,
// single dispatch.

#define T_STEPS 50
#define THETA   0.9999f

// component of a float4 by compile-time index (folds after unroll)
#define F4C(v, c) ((c) == 0 ? (v).x : (c) == 1 ? (v).y : (c) == 2 ? (v).z : (v).w)

// Exact-rounding rate: tbl[c] == c/50.0f computed with a true divide once.
__device__ __forceinline__ float spike_rate(float a, const float* __restrict__ tbl) {
    constexpr float INV = 50.0f / 0.9999f;
    float t = a * INV;
    float c = fminf(fmaxf(floorf(t), 0.0f), 50.0f);
    // fall back to the exact 50-step f32 sim when t is near an integer
    bool risky = (t > 0.5f) && (fabsf(t - rintf(t)) < 2e-4f);
    if (__ballot(risky)) {
        float v = 0.f, cnt = 0.f;
#pragma unroll 1
        for (int k = 0; k < T_STEPS; ++k) {
            v += a;
            float s = (v >= THETA) ? 1.0f : 0.0f;
            v -= s * THETA;
            cnt += s;
        }
        c = cnt;
    }
    return tbl[(int)c];
}

// No-ballot variant: only legal when the input provably cannot sit within
// 2e-4 of an integer boundary in t-units (pooled path: 1.1*k/50, margin 1.1e-3).
__device__ __forceinline__ float spike_rate_nb(float a, const float* __restrict__ tbl) {
    constexpr float INV = 50.0f / 0.9999f;
    float t = a * INV;
    float c = fminf(fmaxf(floorf(t), 0.0f), 50.0f);
    return tbl[(int)c];
}

extern "C" __global__ void __launch_bounds__(1024, 4)
catnet_kernel(const float* __restrict__ x,
              const float* __restrict__ w1, const float* __restrict__ b1,
              const float* __restrict__ w2, const float* __restrict__ b2,
              const float* __restrict__ w3, const float* __restrict__ b3,
              const float* __restrict__ wf, const float* __restrict__ bf,
              float* __restrict__ out)
{
    const int n    = blockIdx.x;
    const int tid  = threadIdx.x;
    const int wave = tid >> 6;
    const int lane = tid & 63;

    __shared__ float  xbar[182];        // [h+1], h in [0,180)
    __shared__ float4 r1qe[4][92];      // [ciq][i] = conv1 rate at even padded H=2i, ci quad
    __shared__ float4 r1qo[4][92];      // [ciq][i] = odd padded H=2i+1
    __shared__ float4 r3q[8][89];       // [ciq][p+1] = pooled rate, ci quad
    __shared__ alignas(16) float r4s[32][83];
    __shared__ float  ratetbl[51];      // exact c/50.0f
    __shared__ float  part[16];

    // zero conv pads + build exact-rate table
    const float4 z4 = make_float4(0.f, 0.f, 0.f, 0.f);
    if (tid < 4)               r1qe[tid][0]       = z4;   // H=0 pad
    if (tid >= 4  && tid < 8)  r1qo[tid - 4][90]  = z4;   // H=181 pad
    if (tid >= 8  && tid < 16) r3q[tid - 8][0]    = z4;   // p_idx=0 pad
    if (tid >= 16 && tid < 24) r3q[tid - 16][88]  = z4;   // p_idx=88 pad
    if (tid == 64)             { xbar[0] = 0.f; xbar[181] = 0.f; }
    if (tid >= 128 && tid < 179) ratetbl[tid - 128] = (float)(tid - 128) / 50.0f;

    // ---- phase 0: time-sum of input, 4 lanes per h, float2 loads ----
    const float* xn = x + (size_t)n * (180 * 50);
    if (tid < 720) {
        const int h = tid >> 2, q = tid & 3;
        const float2* row2 = reinterpret_cast<const float2*>(xn + h * 50);
        float s = 0.f;
        for (int k = q; k < 24; k += 4) { float2 v = row2[k]; s += v.x + v.y; }
        if (q == 0)                     { float2 v = row2[24]; s += v.x + v.y; }
        s += __shfl_xor(s, 1, 4);
        s += __shfl_xor(s, 2, 4);
        if (q == 0) xbar[h + 1] = s;
    }
    __syncthreads();

    // ---- phase 1: conv1 (1->16, k=3, pad=1), /T, +b1, rate ----
    // wave = channel (wave-uniform -> s_load w1/b1, no int div); lanes sweep
    // h in 3 strips of 64 (180 = 64+64+52).
    {
        const int c  = __builtin_amdgcn_readfirstlane(wave);   // 0..15
        const float wA = w1[c*3+0], wB = w1[c*3+1], wC = w1[c*3+2];
        const float bb = b1[c];
#pragma unroll
        for (int i = 0; i < 3; ++i) {
            const int h = i * 64 + lane;
            const bool act = h < 180;
            const int hh = act ? h : 0;
            float a = wA * xbar[hh] + wB * xbar[hh+1] + wC * xbar[hh+2];
            a = a / 50.0f + bb;
            float r = spike_rate(a, ratetbl);
            if (act) {
                int H = hh + 1;
                float* dst = (H & 1) ? (float*)&r1qo[c >> 2][H >> 1]
                                     : (float*)&r1qe[c >> 2][H >> 1];
                dst[c & 3] = r;
            }
        }
    }
    __syncthreads();

    // ---- phase 2: conv2 (16->32, k=9, pad=1) + rate + pool(2)*1.1 + rate ----
    // 8 groups of 128 threads: g = tid>>7 (wave-uniform), p = tid&127 < 87.
    // Thread computes conv2 at h=2p,2p+1 (shared 10-tap window) for 4 out-ch.
    // Per ci-quad: 10 ds_read_b128 window taps. UNROLL 2 over qd.
    {
        const int g   = __builtin_amdgcn_readfirstlane(tid >> 7);   // 0..7
        const int p   = tid & 127;
        const bool act = p < 87;
        const int pr  = act ? p : 0;
        const float* wb = w2 + g * 4 * 144;   // [oc][ci][kh], oc stride 144

        float a0[4], a1[4];
#pragma unroll
        for (int j = 0; j < 4; ++j) { a0[j] = b2[g*4 + j]; a1[j] = a0[j]; }

#pragma unroll 2
        for (int qd = 0; qd < 4; ++qd) {
            float4 we[5], wo[5];
#pragma unroll
            for (int d = 0; d < 5; ++d) { we[d] = r1qe[qd][pr + d]; wo[d] = r1qo[qd][pr + d]; }

#pragma unroll
            for (int c4 = 0; c4 < 4; ++c4) {
                const int ci = qd * 4 + c4;
#pragma unroll
                for (int j = 0; j < 4; ++j) {
                    const float* wj = wb + j * 144 + ci * 9;
#pragma unroll
                    for (int kh = 0; kh < 9; ++kh) {
                        float wv  = wj[kh];
                        float xlo = (kh & 1) ? F4C(wo[kh >> 1], c4)
                                             : F4C(we[kh >> 1], c4);        // tap kh
                        float xhi = (kh & 1) ? F4C(we[(kh + 1) >> 1], c4)
                                             : F4C(wo[kh >> 1], c4);        // tap kh+1
                        a0[j] += wv * xlo;     // h = 2p
                        a1[j] += wv * xhi;     // h = 2p+1
                    }
                }
            }
        }
        float r3t[4];
#pragma unroll
        for (int j = 0; j < 4; ++j) {
            float r20 = spike_rate(a0[j], ratetbl);
            float r21 = spike_rate(a1[j], ratetbl);
            r3t[j] = spike_rate_nb(1.1f * (r20 + r21), ratetbl);
        }
        if (act) r3q[g][p + 1] = make_float4(r3t[0], r3t[1], r3t[2], r3t[3]);
    }
    __syncthreads();

    // ---- phase 4: conv3 (32->32, k=7, pad=1) + rate ----
    // 16 waves = 8 out-ch-groups(4) x 2 h-halves; lanes -> h.
    // Per ci-quad: 7 ds_read_b128 window taps. UNROLL 2 over q.
    {
        const int gg   = __builtin_amdgcn_readfirstlane(wave >> 1);  // 0..7
        const int g4   = gg * 4;
        const int half = wave & 1;
        const int cnt  = half ? 41 : 42;
        const bool act = lane < cnt;
        const int h0   = half * 42 + lane;    // valid max 82; window max 88
        const int hr   = act ? h0 : 0;
        const float* wb = w3 + g4 * 224;      // [oc][ci][kh], oc stride 224

        float a[4];
#pragma unroll
        for (int j = 0; j < 4; ++j) a[j] = b3[g4 + j];

#pragma unroll 2
        for (int q = 0; q < 8; ++q) {
            float4 rv[7];
#pragma unroll
            for (int d = 0; d < 7; ++d) rv[d] = r3q[q][hr + d];

#pragma unroll
            for (int c4 = 0; c4 < 4; ++c4) {
                const int ci = q * 4 + c4;
#pragma unroll
                for (int j = 0; j < 4; ++j) {
                    const float* wj = wb + j * 224 + ci * 7;
#pragma unroll
                    for (int kh = 0; kh < 7; ++kh)
                        a[j] += wj[kh] * F4C(rv[kh], c4);
                }
            }
        }
#pragma unroll
        for (int j = 0; j < 4; ++j) {
            float r = spike_rate(a[j], ratetbl);
            if (act) r4s[g4 + j][h0] = r;
        }
    }
    __syncthreads();

    // ---- phase 5: dense [32*83] -> 4 outputs; 4 waves per output, float4 ----
    {
        const int o = wave >> 2, q = wave & 3;
        const float4* r44 = reinterpret_cast<const float4*>(&r4s[0][0]);
        const float4* wo4 = reinterpret_cast<const float4*>(wf + o * (32 * 83));
        float acc = 0.f;
        for (int j = q * 64 + lane; j < 664; j += 256) {
            float4 rv = r44[j], wv = wo4[j];
            acc += rv.x * wv.x + rv.y * wv.y;
            acc += rv.z * wv.z + rv.w * wv.w;
        }
#pragma unroll
        for (int off = 32; off > 0; off >>= 1)
            acc += __shfl_down(acc, off, 64);
        if (lane == 0) part[wave] = acc;
    }
    __syncthreads();
    if (tid < 4) {
        float s = part[tid*4] + part[tid*4+1] + part[tid*4+2] + part[tid*4+3];
        out[n * 4 + tid] = s + bf[tid];
    }
}

extern "C" void kernel_launch(void* const* d_in, const int* in_sizes, int n_in,
                              void* d_out, int out_size, void* d_ws, size_t ws_size,
                              hipStream_t stream) {
    const float* x  = (const float*)d_in[0];
    const float* w1 = (const float*)d_in[1];
    const float* b1 = (const float*)d_in[2];
    const float* w2 = (const float*)d_in[3];
    const float* b2 = (const float*)d_in[4];
    const float* w3 = (const float*)d_in[5];
    const float* b3 = (const float*)d_in[6];
    const float* wf = (const float*)d_in[7];
    const float* bf = (const float*)d_in[8];
    float* outp = (float*)d_out;

    catnet_kernel<<<dim3(256), dim3(1024), 0, stream>>>(
        x, w1, b1, w2, b2, w3, b3, wf, bf, outp);
}

// Round 16
// 97.192 us; speedup vs baseline: 1.0402x; 1.0402x over previous
//
#include <hip/hip_runtime.h>

// CatNet_76553497084407 — SLAYER-style spiking CNN, fully collapsed over time.
//
// FINAL (R23 = R21 restored, best of session): 97.1us bench, absmax 0.0
// (bit-exact vs JAX reference), kernel ~32-33us. Baseline was 104.3us.
// R22's unroll-2 experiment was null-to-negative (101.1) -> reverted.
//
// SESSION MODEL (16 rounds of counter evidence): the kernel is wave-ISSUE-
// SLOT + latency bound at ~2.2x the pure-issue floor.
//   time ~ slots: R9 +DS -> +16%; R12 +VMEM -> +170%; R13 -75% DS -> -15%;
//   R17 +25% work at verified 2x occupancy -> +23%; R20/R21 cuts -> wins.
//   null: R8 (-conflicts, -divide), R11 (+barrier domains), R15 (prefetch),
//   R22 (unroll-2). negative: R14 (slot cut idling waves), R16 (SMEM->VMEM).
//   excluded: packed fp32 (157.3 TF IS the unpacked rate; 2/2 toolchain
//   kills on ext_vector f32 arithmetic); MFMA (k/50 exactness, no fp32 MFMA).
//
// Kernel structure:
//   * Only spike COUNTS flow between layers -> T=50 never materialized.
//   * ci-quad float4 interstage layouts: one ds_read_b128 = one window tap
//     x 4 input channels (the single biggest win of the session, -75% DS).
//   * conv2+pool fused: thread computes h=2p,2p+1 from a shared 10-tap
//     window, rates, pools in-register.
//   * wave-uniform s_load weights; wave=channel phase 1; 16-wave mapping.
//   * exact-rounding spike_rate: c/50.0f via 51-entry LDS table (true
//     divides), 2e-4 risky threshold with 50-step f32 sim fallback,
//     no-ballot variant for the pooled path (margin 1.1e-3).
//   * float4 dense epilogue; single dispatch, grid 256 x 1024.

#define T_STEPS 50
#define THETA   0.9999f

// component of a float4 by compile-time index (folds after unroll)
#define F4C(v, c) ((c) == 0 ? (v).x : (c) == 1 ? (v).y : (c) == 2 ? (v).z : (v).w)

// Exact-rounding rate: tbl[c] == c/50.0f computed with a true divide once.
__device__ __forceinline__ float spike_rate(float a, const float* __restrict__ tbl) {
    constexpr float INV = 50.0f / 0.9999f;
    float t = a * INV;
    float c = fminf(fmaxf(floorf(t), 0.0f), 50.0f);
    // fall back to the exact 50-step f32 sim when t is near an integer
    bool risky = (t > 0.5f) && (fabsf(t - rintf(t)) < 2e-4f);
    if (__ballot(risky)) {
        float v = 0.f, cnt = 0.f;
#pragma unroll 1
        for (int k = 0; k < T_STEPS; ++k) {
            v += a;
            float s = (v >= THETA) ? 1.0f : 0.0f;
            v -= s * THETA;
            cnt += s;
        }
        c = cnt;
    }
    return tbl[(int)c];
}

// No-ballot variant: only legal when the input provably cannot sit within
// 2e-4 of an integer boundary in t-units (pooled path: 1.1*k/50, margin 1.1e-3).
__device__ __forceinline__ float spike_rate_nb(float a, const float* __restrict__ tbl) {
    constexpr float INV = 50.0f / 0.9999f;
    float t = a * INV;
    float c = fminf(fmaxf(floorf(t), 0.0f), 50.0f);
    return tbl[(int)c];
}

extern "C" __global__ void __launch_bounds__(1024, 4)
catnet_kernel(const float* __restrict__ x,
              const float* __restrict__ w1, const float* __restrict__ b1,
              const float* __restrict__ w2, const float* __restrict__ b2,
              const float* __restrict__ w3, const float* __restrict__ b3,
              const float* __restrict__ wf, const float* __restrict__ bf,
              float* __restrict__ out)
{
    const int n    = blockIdx.x;
    const int tid  = threadIdx.x;
    const int wave = tid >> 6;
    const int lane = tid & 63;

    __shared__ float  xbar[182];        // [h+1], h in [0,180)
    __shared__ float4 r1qe[4][92];      // [ciq][i] = conv1 rate at even padded H=2i, ci quad
    __shared__ float4 r1qo[4][92];      // [ciq][i] = odd padded H=2i+1
    __shared__ float4 r3q[8][89];       // [ciq][p+1] = pooled rate, ci quad
    __shared__ alignas(16) float r4s[32][83];
    __shared__ float  ratetbl[51];      // exact c/50.0f
    __shared__ float  part[16];

    // zero conv pads + build exact-rate table
    const float4 z4 = make_float4(0.f, 0.f, 0.f, 0.f);
    if (tid < 4)               r1qe[tid][0]       = z4;   // H=0 pad
    if (tid >= 4  && tid < 8)  r1qo[tid - 4][90]  = z4;   // H=181 pad
    if (tid >= 8  && tid < 16) r3q[tid - 8][0]    = z4;   // p_idx=0 pad
    if (tid >= 16 && tid < 24) r3q[tid - 16][88]  = z4;   // p_idx=88 pad
    if (tid == 64)             { xbar[0] = 0.f; xbar[181] = 0.f; }
    if (tid >= 128 && tid < 179) ratetbl[tid - 128] = (float)(tid - 128) / 50.0f;

    // ---- phase 0: time-sum of input, 4 lanes per h, float2 loads ----
    const float* xn = x + (size_t)n * (180 * 50);
    if (tid < 720) {
        const int h = tid >> 2, q = tid & 3;
        const float2* row2 = reinterpret_cast<const float2*>(xn + h * 50);
        float s = 0.f;
        for (int k = q; k < 24; k += 4) { float2 v = row2[k]; s += v.x + v.y; }
        if (q == 0)                     { float2 v = row2[24]; s += v.x + v.y; }
        s += __shfl_xor(s, 1, 4);
        s += __shfl_xor(s, 2, 4);
        if (q == 0) xbar[h + 1] = s;
    }
    __syncthreads();

    // ---- phase 1: conv1 (1->16, k=3, pad=1), /T, +b1, rate ----
    // wave = channel (wave-uniform -> s_load w1/b1, no int div); lanes sweep
    // h in 3 strips of 64 (180 = 64+64+52).
    {
        const int c  = __builtin_amdgcn_readfirstlane(wave);   // 0..15
        const float wA = w1[c*3+0], wB = w1[c*3+1], wC = w1[c*3+2];
        const float bb = b1[c];
#pragma unroll
        for (int i = 0; i < 3; ++i) {
            const int h = i * 64 + lane;
            const bool act = h < 180;
            const int hh = act ? h : 0;
            float a = wA * xbar[hh] + wB * xbar[hh+1] + wC * xbar[hh+2];
            a = a / 50.0f + bb;
            float r = spike_rate(a, ratetbl);
            if (act) {
                int H = hh + 1;
                float* dst = (H & 1) ? (float*)&r1qo[c >> 2][H >> 1]
                                     : (float*)&r1qe[c >> 2][H >> 1];
                dst[c & 3] = r;
            }
        }
    }
    __syncthreads();

    // ---- phase 2: conv2 (16->32, k=9, pad=1) + rate + pool(2)*1.1 + rate ----
    // 8 groups of 128 threads: g = tid>>7 (wave-uniform), p = tid&127 < 87.
    // Thread computes conv2 at h=2p,2p+1 (shared 10-tap window) for 4 out-ch.
    // Per ci-quad: 10 ds_read_b128 = window taps for 4 input channels.
    // Tap d (padded H=2p+d): d even -> F4C(we[d/2]), d odd -> F4C(wo[(d-1)/2]).
    {
        const int g   = __builtin_amdgcn_readfirstlane(tid >> 7);   // 0..7
        const int p   = tid & 127;
        const bool act = p < 87;
        const int pr  = act ? p : 0;
        const float* wb = w2 + g * 4 * 144;   // [oc][ci][kh], oc stride 144

        float a0[4], a1[4];
#pragma unroll
        for (int j = 0; j < 4; ++j) { a0[j] = b2[g*4 + j]; a1[j] = a0[j]; }

#pragma unroll 1
        for (int qd = 0; qd < 4; ++qd) {
            float4 we[5], wo[5];
#pragma unroll
            for (int d = 0; d < 5; ++d) { we[d] = r1qe[qd][pr + d]; wo[d] = r1qo[qd][pr + d]; }

#pragma unroll
            for (int c4 = 0; c4 < 4; ++c4) {
                const int ci = qd * 4 + c4;
#pragma unroll
                for (int j = 0; j < 4; ++j) {
                    const float* wj = wb + j * 144 + ci * 9;
#pragma unroll
                    for (int kh = 0; kh < 9; ++kh) {
                        float wv  = wj[kh];
                        float xlo = (kh & 1) ? F4C(wo[kh >> 1], c4)
                                             : F4C(we[kh >> 1], c4);        // tap kh
                        float xhi = (kh & 1) ? F4C(we[(kh + 1) >> 1], c4)
                                             : F4C(wo[kh >> 1], c4);        // tap kh+1
                        a0[j] += wv * xlo;     // h = 2p
                        a1[j] += wv * xhi;     // h = 2p+1
                    }
                }
            }
        }
        float r3t[4];
#pragma unroll
        for (int j = 0; j < 4; ++j) {
            float r20 = spike_rate(a0[j], ratetbl);
            float r21 = spike_rate(a1[j], ratetbl);
            r3t[j] = spike_rate_nb(1.1f * (r20 + r21), ratetbl);
        }
        if (act) r3q[g][p + 1] = make_float4(r3t[0], r3t[1], r3t[2], r3t[3]);
    }
    __syncthreads();

    // ---- phase 4: conv3 (32->32, k=7, pad=1) + rate ----
    // 16 waves = 8 out-ch-groups(4) x 2 h-halves; lanes -> h.
    // Per ci-quad: 7 ds_read_b128 window taps (4 input channels each).
    {
        const int gg   = __builtin_amdgcn_readfirstlane(wave >> 1);  // 0..7
        const int g4   = gg * 4;
        const int half = wave & 1;
        const int cnt  = half ? 41 : 42;
        const bool act = lane < cnt;
        const int h0   = half * 42 + lane;    // valid max 82; window max 88
        const int hr   = act ? h0 : 0;
        const float* wb = w3 + g4 * 224;      // [oc][ci][kh], oc stride 224

        float a[4];
#pragma unroll
        for (int j = 0; j < 4; ++j) a[j] = b3[g4 + j];

#pragma unroll 1
        for (int q = 0; q < 8; ++q) {
            float4 rv[7];
#pragma unroll
            for (int d = 0; d < 7; ++d) rv[d] = r3q[q][hr + d];

#pragma unroll
            for (int c4 = 0; c4 < 4; ++c4) {
                const int ci = q * 4 + c4;
#pragma unroll
                for (int j = 0; j < 4; ++j) {
                    const float* wj = wb + j * 224 + ci * 7;
#pragma unroll
                    for (int kh = 0; kh < 7; ++kh)
                        a[j] += wj[kh] * F4C(rv[kh], c4);
                }
            }
        }
#pragma unroll
        for (int j = 0; j < 4; ++j) {
            float r = spike_rate(a[j], ratetbl);
            if (act) r4s[g4 + j][h0] = r;
        }
    }
    __syncthreads();

    // ---- phase 5: dense [32*83] -> 4 outputs; 4 waves per output, float4 ----
    {
        const int o = wave >> 2, q = wave & 3;
        const float4* r44 = reinterpret_cast<const float4*>(&r4s[0][0]);
        const float4* wo4 = reinterpret_cast<const float4*>(wf + o * (32 * 83));
        float acc = 0.f;
        for (int j = q * 64 + lane; j < 664; j += 256) {
            float4 rv = r44[j], wv = wo4[j];
            acc += rv.x * wv.x + rv.y * wv.y;
            acc += rv.z * wv.z + rv.w * wv.w;
        }
#pragma unroll
        for (int off = 32; off > 0; off >>= 1)
            acc += __shfl_down(acc, off, 64);
        if (lane == 0) part[wave] = acc;
    }
    __syncthreads();
    if (tid < 4) {
        float s = part[tid*4] + part[tid*4+1] + part[tid*4+2] + part[tid*4+3];
        out[n * 4 + tid] = s + bf[tid];
    }
}

extern "C" void kernel_launch(void* const* d_in, const int* in_sizes, int n_in,
                              void* d_out, int out_size, void* d_ws, size_t ws_size,
                              hipStream_t stream) {
    const float* x  = (const float*)d_in[0];
    const float* w1 = (const float*)d_in[1];
    const float* b1 = (const float*)d_in[2];
    const float* w2 = (const float*)d_in[3];
    const float* b2 = (const float*)d_in[4];
    const float* w3 = (const float*)d_in[5];
    const float* b3 = (const float*)d_in[6];
    const float* wf = (const float*)d_in[7];
    const float* bf = (const float*)d_in[8];
    float* outp = (float*)d_out;

    catnet_kernel<<<dim3(256), dim3(1024), 0, stream>>>(
        x, w1, b1, w2, b2, w3, b3, wf, bf, outp);
}